// Round 3
// baseline (113.387 us; speedup 1.0000x reference)
//
#include <hip/hip_runtime.h>

// OpenBoundary neighbor list, N=8192, cutoff=5.0, max_neighbours=32.
// Outputs (int32, concat): to_idx[8192][32] | cell_indices[8192][32][3]=0 | actual_max
//
// R12 = R11 with two structural changes driven by the dispatch-overhead theory
// (our 3 kernels model out at ~9us of GPU work; the rest of dur_us is harness
// poison fills + per-dispatch graph overhead):
//   1. C=15 -> C=16 cells (width 80/16 = 5.0 == cutoff, exact-floor safe with
//      INVW=0.2f): candidates/point 66 -> ~54, so ~90% of waves do ONE 64-lane
//      sweep and skip the ballot/mbcnt/LDS-hitbuf path (the bitonic sort itself
//      compacts hit?j:INT_MAX).
//   2. finalize kernel removed (3 dispatches -> 2): scratch moves to d_ws
//      (the 256MiB ws poison fill in rocprof proves d_ws is large; we need
//      ~153KB), each query block zeroes its own 1.5KB cell_indices slice, and
//      actual_max is reduced in-query by a two-level last-block-done ladder
//      (64-contender counters -- NOT the 2048-contender same-address atomic
//      that cost +17us in R8/R10; no spinning, so dispatch-order independent).
//
// (R14: second resubmission — R12/R13 benches were lost to infra failures
// (GPUAcquisitionTimeout, Trio ExceptionGroup). Source identical to keep the
// A/B against R11's 75.8us clean.)

constexpr int   N     = 8192;
constexpr int   MAXNB = 32;
constexpr float CUT2  = 25.0f;     // 5.0^2 exact
constexpr int   C     = 16;        // cells/dim; width 80/16 = 5.0 == cutoff
constexpr int   NCP   = C * C * C; // 4096 cells, exact (no padding)
constexpr float INVW  = 0.2f;      // 16/80; never misclassifies a 5k boundary
constexpr int   QBLOCKS = N / 4;   // 2048 query blocks (4 waves each)

__device__ __forceinline__ int cell_coord(float v) {
    int c = (int)(v * INVW);
    return c > C - 1 ? C - 1 : c;  // v in [0,80): clamp boundary rounding
}

// ---------- build: hist + shfl-scan + scatter, one single-block kernel ----------
__global__ __launch_bounds__(1024) void build_kernel(const float* __restrict__ pos,
                                                     int* __restrict__ start_g,
                                                     float4* __restrict__ sorted,
                                                     int* __restrict__ done) {
    __shared__ int cnt[NCP];       // 16 KB: hist, then exclusive starts
    __shared__ int wsum[16];       // per-wave totals
    const int t    = threadIdx.x;
    const int lane = t & 63;
    const int wv   = t >> 6;

    if (t < 33) done[t] = 0;       // done1[32] + done2 for query's reduction ladder

    #pragma unroll
    for (int k = t; k < NCP; k += 1024) cnt[k] = 0;
    __syncthreads();

    float x[8], y[8], z[8];
    int cid[8], rnk[8];
    #pragma unroll
    for (int q = 0; q < 8; ++q) {            // coalesced: i = q*1024 + t
        const int i = q * 1024 + t;
        x[q] = pos[3 * i + 0];
        y[q] = pos[3 * i + 1];
        z[q] = pos[3 * i + 2];
        cid[q] = (cell_coord(z[q]) << 8) | (cell_coord(y[q]) << 4) | cell_coord(x[q]);
        rnk[q] = atomicAdd(&cnt[cid[q]], 1);
    }
    __syncthreads();

    // Scan of 4096 counts, 4 per thread: thread-local sum -> wave shfl-scan ->
    // serial 16-entry wave-offset scan -> recombine. 2 barriers total.
    int c[4], pre[4], s0 = 0;
    #pragma unroll
    for (int k = 0; k < 4; ++k) { c[k] = cnt[4 * t + k]; pre[k] = s0; s0 += c[k]; }
    int inc = s0;                            // inclusive prefix within wave
    #pragma unroll
    for (int off = 1; off < 64; off <<= 1) {
        const int v = __shfl_up(inc, off);
        if (lane >= off) inc += v;
    }
    if (lane == 63) wsum[wv] = inc;          // wave total
    __syncthreads();
    if (t == 0) {                            // exclusive scan of 16 wave totals
        int acc = 0;
        #pragma unroll
        for (int k = 0; k < 16; ++k) { const int tmp = wsum[k]; wsum[k] = acc; acc += tmp; }
    }
    __syncthreads();
    const int excl = wsum[wv] + (inc - s0);  // global exclusive thread prefix
    #pragma unroll
    for (int k = 0; k < 4; ++k) {
        cnt[4 * t + k]     = excl + pre[k];  // in-place: cnt -> exclusive start
        start_g[4 * t + k] = excl + pre[k];
    }
    if (t == 0) start_g[NCP] = N;
    __syncthreads();

    #pragma unroll
    for (int q = 0; q < 8; ++q) {            // atomic-free scatter from registers
        const int p = cnt[cid[q]] + rnk[q];
        sorted[p] = make_float4(x[q], y[q], z[q], __int_as_float(q * 1024 + t));
    }
}

// ---------- query: one wave per point + fused zeroing + fused max-reduction ----------
__global__ __launch_bounds__(256) void query_kernel(const float* __restrict__ pos,
                                                    const float4* __restrict__ sorted,
                                                    const int* __restrict__ start_g,
                                                    int* __restrict__ out_idx,
                                                    int4* __restrict__ cell4,
                                                    int* __restrict__ blockmax,
                                                    int* __restrict__ done1,
                                                    int* __restrict__ done2,
                                                    int* __restrict__ groupmax,
                                                    int* __restrict__ out_max) {
    __shared__ int hitbuf[4][64];
    __shared__ int wmax[4];
    const int lane = threadIdx.x & 63;
    const int wave = threadIdx.x >> 6;

    // Fused finalize part 1: zero this block's cell_indices slice (4 rows x 32 x 3
    // ints = 96 int4). Independent stores, no barrier needed.
    if (threadIdx.x < 96) cell4[blockIdx.x * 96 + threadIdx.x] = make_int4(0, 0, 0, 0);

    // Force p (and everything derived) into SGPRs: it is wave-uniform.
    const int p = __builtin_amdgcn_readfirstlane((int)blockIdx.x * 4 + wave);

    const float x = pos[3 * p + 0];
    const float y = pos[3 * p + 1];
    const float z = pos[3 * p + 2];
    const int cx = cell_coord(x), cy = cell_coord(y), cz = cell_coord(z);
    // 3 distinct clamped rows per dim; any clamp-extra cell is >= 5.0 away in
    // that dim with strict inequality, so f32 r2 > 25 rejects all its points
    // (no duplicates, no holes; cell_coord == exact floor(v/5) for all f32 v).
    int xa = cx - 1; xa = xa < 0 ? 0 : (xa > C - 3 ? C - 3 : xa);
    int ya = cy - 1; ya = ya < 0 ? 0 : (ya > C - 3 ? C - 3 : ya);
    int za = cz - 1; za = za < 0 ? 0 : (za > C - 3 ? C - 3 : za);

    // Prefetch all 9 segment bounds (wave-uniform -> s_loads, batched).
    int bb[9], pre[10];
    pre[0] = 0;
    #pragma unroll
    for (int s = 0; s < 9; ++s) {
        const int rowb = ((za + s / 3) << 8) + ((ya + s % 3) << 4) + xa;
        bb[s] = start_g[rowb];
        pre[s + 1] = pre[s] + (start_g[rowb + 3] - bb[s]);   // 3 x-cells contiguous
    }
    const int total = pre[9];

    int count = 0;                 // full unclamped hit count
    int v = 0x7fffffff;            // sort key (INT_MAX padding)

    if (total <= 64) {
        // Fast path (~90% of waves at C=16, lambda~54): one sweep, no hitbuf.
        // The bitonic sort itself compacts hit ? j : INT_MAX into ascending order.
        int idx = 0;
        #pragma unroll
        for (int s = 0; s < 9; ++s) {
            const bool in_s = (lane >= pre[s]) && (lane < pre[s + 1]);
            idx = in_s ? (bb[s] + (lane - pre[s])) : idx;
        }
        const float4 o = sorted[idx];
        // numpy f32 rounding: no FMA, ((dx^2+dy^2)+dz^2)
        const float dx = __fsub_rn(x, o.x);
        const float dy = __fsub_rn(y, o.y);
        const float dz = __fsub_rn(z, o.z);
        const float r2 = __fadd_rn(__fadd_rn(__fmul_rn(dx, dx), __fmul_rn(dy, dy)),
                                   __fmul_rn(dz, dz));
        const int j = __float_as_int(o.w);
        const bool hit = (lane < total) && (r2 <= CUT2) && (j != p);
        count = __popcll(__ballot(hit));
        v = hit ? j : 0x7fffffff;
    } else {
        // General path: ballot-compact into per-wave LDS buffer.
        for (int base = 0; base < total; base += 64) {
            const int l = base + lane;
            int idx = 0;
            #pragma unroll
            for (int s = 0; s < 9; ++s) {
                const bool in_s = (l >= pre[s]) && (l < pre[s + 1]);
                idx = in_s ? (bb[s] + (l - pre[s])) : idx;
            }
            const float4 o = sorted[idx];
            const float dx = __fsub_rn(x, o.x);
            const float dy = __fsub_rn(y, o.y);
            const float dz = __fsub_rn(z, o.z);
            const float r2 = __fadd_rn(__fadd_rn(__fmul_rn(dx, dx), __fmul_rn(dy, dy)),
                                       __fmul_rn(dz, dz));
            const int j = __float_as_int(o.w);
            const bool hit = (l < total) && (r2 <= CUT2) && (j != p);
            const unsigned long long m = __ballot(hit);
            if (hit) {
                const int pr = __builtin_amdgcn_mbcnt_hi(
                    (unsigned int)(m >> 32),
                    __builtin_amdgcn_mbcnt_lo((unsigned int)m, 0u));
                const int slot = count + pr;
                if (slot < 64) hitbuf[wave][slot] = j;
            }
            count += __popcll(m);
        }
        const int mcount = count < 64 ? count : 64;
        v = (lane < mcount) ? hitbuf[wave][lane] : 0x7fffffff;
    }

    // 64-lane bitonic sort ascending -> exact argwhere order.
    #pragma unroll
    for (int k = 2; k <= 64; k <<= 1) {
        #pragma unroll
        for (int jj = k >> 1; jj >= 1; jj >>= 1) {
            const int pv = __shfl_xor(v, jj);
            const bool keepmin = ((lane & jj) == 0) == ((lane & k) == 0);
            v = keepmin ? min(v, pv) : max(v, pv);
        }
    }
    if (lane < MAXNB) out_idx[p * MAXNB + lane] = (lane < count) ? v : -1;

    // per-block max of full counts (count is wave-uniform)
    if (lane == 0) wmax[wave] = count;
    __syncthreads();

    // Fused finalize part 2: two-level last-block-done reduction for actual_max.
    // Level 1: 32 groups of 64 blocks (64-contender counters). Level 2: 32
    // contenders on one counter. Writers never spin -> no residency/dispatch-
    // order assumption (Guideline 16). Release on the fetch_add orders the
    // preceding blockmax/groupmax store; winner's acquire + agent-scope atomic
    // loads make the data visible across XCDs.
    if (wave == 0) {
        const int b = (int)blockIdx.x;
        const int g = b >> 6;
        const int bmax = max(max(wmax[0], wmax[1]), max(wmax[2], wmax[3]));
        int old = 0;
        if (lane == 0) {
            __hip_atomic_store(&blockmax[b], bmax, __ATOMIC_RELAXED, __HIP_MEMORY_SCOPE_AGENT);
            old = __hip_atomic_fetch_add(&done1[g], 1, __ATOMIC_ACQ_REL, __HIP_MEMORY_SCOPE_AGENT);
        }
        old = __shfl(old, 0);
        if (old == 63) {                     // last block of this 64-block group
            int gm = __hip_atomic_load(&blockmax[(g << 6) + lane],
                                       __ATOMIC_RELAXED, __HIP_MEMORY_SCOPE_AGENT);
            #pragma unroll
            for (int off = 32; off > 0; off >>= 1) gm = max(gm, __shfl_xor(gm, off));
            int old2 = 0;
            if (lane == 0) {
                __hip_atomic_store(&groupmax[g], gm, __ATOMIC_RELAXED, __HIP_MEMORY_SCOPE_AGENT);
                old2 = __hip_atomic_fetch_add(done2, 1, __ATOMIC_ACQ_REL, __HIP_MEMORY_SCOPE_AGENT);
            }
            old2 = __shfl(old2, 0);
            if (old2 == 31) {                // very last group -> write the scalar
                int m2 = (lane < 32)
                    ? __hip_atomic_load(&groupmax[lane], __ATOMIC_RELAXED, __HIP_MEMORY_SCOPE_AGENT)
                    : 0;
                #pragma unroll
                for (int off = 32; off > 0; off >>= 1) m2 = max(m2, __shfl_xor(m2, off));
                if (lane == 0) *out_max = m2;
            }
        }
    }
}

extern "C" void kernel_launch(void* const* d_in, const int* in_sizes, int n_in,
                              void* d_out, int out_size, void* d_ws, size_t ws_size,
                              hipStream_t stream) {
    const float* pos = (const float*)d_in[0];   // [8192, 3] f32
    int* out = (int*)d_out;

    int*  out_idx = out;                        // [N*32]
    int4* cell4   = (int4*)(out + N * MAXNB);   // cell_indices region (zeroed by query)
    int*  out_max = out + N * MAXNB * 4;        // scalar

    // Scratch now lives entirely in d_ws (~153 KB; the 256 MiB poison fill of
    // d_ws in rocprof shows it is far larger). Every byte used is written
    // before it is read within each graph replay.
    char*   ws       = (char*)d_ws;
    float4* sorted   = (float4*)ws;             // 131072 B, 16B aligned
    int*    start_g  = (int*)(ws + 131072);     // 4097 ints
    int*    blockmax = (int*)(ws + 147968);     // 2048 ints
    int*    groupmax = (int*)(ws + 156160);     // 32 ints
    int*    done     = (int*)(ws + 156288);     // done1[32] + done2[1], zeroed by build

    build_kernel<<<1, 1024, 0, stream>>>(pos, start_g, sorted, done);
    query_kernel<<<QBLOCKS, 256, 0, stream>>>(pos, sorted, start_g, out_idx, cell4,
                                              blockmax, done, done + 32, groupmax, out_max);
}

// Round 6
// 73.254 us; speedup vs baseline: 1.5479x; 1.5479x over previous
//
#include <hip/hip_runtime.h>

// OpenBoundary neighbor list, N=8192, cutoff=5.0, max_neighbours=32.
// Outputs (int32, concat): to_idx[8192][32] | cell_indices[8192][32][3]=0 | actual_max
//
// R15 post-mortem of R12 (113.4us, query=52us): the fused two-level ACQ_REL
// agent-scope atomic ladder stalled query (VALUBusy 4.5%, occ 24%, BW 1.2% --
// pure fence stall). Agent-scope acq/rel RMWs on multi-XCD gfx950 drag
// cache-maintenance (L1 inv / L2 wb) per block x 2048: ~50us. Atomics were
// the wrong tool; fences, not contention, were the cost.
//
// R15 = R12 minus the ladder:
//   build    (1 block x 1024): LDS hist -> shfl-scan -> atomic-free scatter.
//   query    (2048 x 256): C=16 fast path (~90% of waves: ONE 64-lane sweep,
//            no LDS hitbuf), fused zeroing of its own 1.5KB cell_indices
//            slice, per-wave count -> plain store wavemax[p]. No barrier,
//            no atomics.
//   maxred   (1 block x 1024): reduce 8192 wave counts -> actual_max.
//            Tiny 3rd dispatch (~2-3us) instead of 52us of fences.
//
// (R17: third resubmission — R15/R16 benches lost to GPUAcquisitionTimeout.
// Source identical to keep the A/B against R12's 113.4us / R11's 75.8us clean.)

constexpr int   N     = 8192;
constexpr int   MAXNB = 32;
constexpr float CUT2  = 25.0f;     // 5.0^2 exact
constexpr int   C     = 16;        // cells/dim; width 80/16 = 5.0 == cutoff
constexpr int   NCP   = C * C * C; // 4096 cells, exact
constexpr float INVW  = 0.2f;      // 16/80; exact floor(v/5) for all f32 v in [0,80)
constexpr int   QBLOCKS = N / 4;   // 2048 query blocks (4 waves each)

__device__ __forceinline__ int cell_coord(float v) {
    int c = (int)(v * INVW);
    return c > C - 1 ? C - 1 : c;  // v in [0,80): clamp boundary rounding
}

// ---------- build: hist + shfl-scan + scatter, one single-block kernel ----------
__global__ __launch_bounds__(1024) void build_kernel(const float* __restrict__ pos,
                                                     int* __restrict__ start_g,
                                                     float4* __restrict__ sorted) {
    __shared__ int cnt[NCP];       // 16 KB: hist, then exclusive starts
    __shared__ int wsum[16];       // per-wave totals
    const int t    = threadIdx.x;
    const int lane = t & 63;
    const int wv   = t >> 6;

    #pragma unroll
    for (int k = t; k < NCP; k += 1024) cnt[k] = 0;
    __syncthreads();

    float x[8], y[8], z[8];
    int cid[8], rnk[8];
    #pragma unroll
    for (int q = 0; q < 8; ++q) {            // coalesced: i = q*1024 + t
        const int i = q * 1024 + t;
        x[q] = pos[3 * i + 0];
        y[q] = pos[3 * i + 1];
        z[q] = pos[3 * i + 2];
        cid[q] = (cell_coord(z[q]) << 8) | (cell_coord(y[q]) << 4) | cell_coord(x[q]);
        rnk[q] = atomicAdd(&cnt[cid[q]], 1);
    }
    __syncthreads();

    // Scan of 4096 counts, 4 per thread: thread-local sum -> wave shfl-scan ->
    // serial 16-entry wave-offset scan -> recombine. 2 barriers total.
    int c[4], pre[4], s0 = 0;
    #pragma unroll
    for (int k = 0; k < 4; ++k) { c[k] = cnt[4 * t + k]; pre[k] = s0; s0 += c[k]; }
    int inc = s0;                            // inclusive prefix within wave
    #pragma unroll
    for (int off = 1; off < 64; off <<= 1) {
        const int v = __shfl_up(inc, off);
        if (lane >= off) inc += v;
    }
    if (lane == 63) wsum[wv] = inc;          // wave total
    __syncthreads();
    if (t == 0) {                            // exclusive scan of 16 wave totals
        int acc = 0;
        #pragma unroll
        for (int k = 0; k < 16; ++k) { const int tmp = wsum[k]; wsum[k] = acc; acc += tmp; }
    }
    __syncthreads();
    const int excl = wsum[wv] + (inc - s0);  // global exclusive thread prefix
    #pragma unroll
    for (int k = 0; k < 4; ++k) {
        cnt[4 * t + k]     = excl + pre[k];  // in-place: cnt -> exclusive start
        start_g[4 * t + k] = excl + pre[k];
    }
    if (t == 0) start_g[NCP] = N;
    __syncthreads();

    #pragma unroll
    for (int q = 0; q < 8; ++q) {            // atomic-free scatter from registers
        const int p = cnt[cid[q]] + rnk[q];
        sorted[p] = make_float4(x[q], y[q], z[q], __int_as_float(q * 1024 + t));
    }
}

// ---------- query: one wave per point + fused cell_indices zeroing ----------
__global__ __launch_bounds__(256) void query_kernel(const float* __restrict__ pos,
                                                    const float4* __restrict__ sorted,
                                                    const int* __restrict__ start_g,
                                                    int* __restrict__ out_idx,
                                                    int4* __restrict__ cell4,
                                                    int* __restrict__ wavemax) {
    __shared__ int hitbuf[4][64];  // slow path only
    const int lane = threadIdx.x & 63;
    const int wave = threadIdx.x >> 6;

    // Fused finalize part 1: zero this block's cell_indices slice (4 rows x 32 x 3
    // ints = 96 int4 = 1536 B contiguous). Independent stores, no barrier.
    if (threadIdx.x < 96) cell4[blockIdx.x * 96 + threadIdx.x] = make_int4(0, 0, 0, 0);

    // Force p (and everything derived) into SGPRs: it is wave-uniform.
    const int p = __builtin_amdgcn_readfirstlane((int)blockIdx.x * 4 + wave);

    const float x = pos[3 * p + 0];
    const float y = pos[3 * p + 1];
    const float z = pos[3 * p + 2];
    const int cx = cell_coord(x), cy = cell_coord(y), cz = cell_coord(z);
    // 3 distinct clamped rows per dim; any clamp-extra cell is >= 5.0 away in
    // that dim with strict inequality, so f32 r2 > 25 rejects all its points
    // (no duplicates, no holes; cell_coord == exact floor(v/5) for all f32 v).
    int xa = cx - 1; xa = xa < 0 ? 0 : (xa > C - 3 ? C - 3 : xa);
    int ya = cy - 1; ya = ya < 0 ? 0 : (ya > C - 3 ? C - 3 : ya);
    int za = cz - 1; za = za < 0 ? 0 : (za > C - 3 ? C - 3 : za);

    // Prefetch all 9 segment bounds (wave-uniform -> s_loads, batched).
    int bb[9], pre[10];
    pre[0] = 0;
    #pragma unroll
    for (int s = 0; s < 9; ++s) {
        const int rowb = ((za + s / 3) << 8) + ((ya + s % 3) << 4) + xa;
        bb[s] = start_g[rowb];
        pre[s + 1] = pre[s] + (start_g[rowb + 3] - bb[s]);   // 3 x-cells contiguous
    }
    const int total = pre[9];

    int count = 0;                 // full unclamped hit count
    int v = 0x7fffffff;            // sort key (INT_MAX padding)

    if (total <= 64) {
        // Fast path (~90% of waves at C=16, lambda~54): one sweep, no hitbuf.
        // The bitonic sort itself compacts hit ? j : INT_MAX into ascending order.
        int idx = 0;
        #pragma unroll
        for (int s = 0; s < 9; ++s) {
            const bool in_s = (lane >= pre[s]) && (lane < pre[s + 1]);
            idx = in_s ? (bb[s] + (lane - pre[s])) : idx;
        }
        const float4 o = sorted[idx];
        // numpy f32 rounding: no FMA, ((dx^2+dy^2)+dz^2)
        const float dx = __fsub_rn(x, o.x);
        const float dy = __fsub_rn(y, o.y);
        const float dz = __fsub_rn(z, o.z);
        const float r2 = __fadd_rn(__fadd_rn(__fmul_rn(dx, dx), __fmul_rn(dy, dy)),
                                   __fmul_rn(dz, dz));
        const int j = __float_as_int(o.w);
        const bool hit = (lane < total) && (r2 <= CUT2) && (j != p);
        count = __popcll(__ballot(hit));
        v = hit ? j : 0x7fffffff;
    } else {
        // General path: ballot-compact into per-wave LDS buffer.
        for (int base = 0; base < total; base += 64) {
            const int l = base + lane;
            int idx = 0;
            #pragma unroll
            for (int s = 0; s < 9; ++s) {
                const bool in_s = (l >= pre[s]) && (l < pre[s + 1]);
                idx = in_s ? (bb[s] + (l - pre[s])) : idx;
            }
            const float4 o = sorted[idx];
            const float dx = __fsub_rn(x, o.x);
            const float dy = __fsub_rn(y, o.y);
            const float dz = __fsub_rn(z, o.z);
            const float r2 = __fadd_rn(__fadd_rn(__fmul_rn(dx, dx), __fmul_rn(dy, dy)),
                                       __fmul_rn(dz, dz));
            const int j = __float_as_int(o.w);
            const bool hit = (l < total) && (r2 <= CUT2) && (j != p);
            const unsigned long long m = __ballot(hit);
            if (hit) {
                const int pr = __builtin_amdgcn_mbcnt_hi(
                    (unsigned int)(m >> 32),
                    __builtin_amdgcn_mbcnt_lo((unsigned int)m, 0u));
                const int slot = count + pr;
                if (slot < 64) hitbuf[wave][slot] = j;
            }
            count += __popcll(m);
        }
        const int mcount = count < 64 ? count : 64;
        v = (lane < mcount) ? hitbuf[wave][lane] : 0x7fffffff;
    }

    // 64-lane bitonic sort ascending -> exact argwhere order.
    #pragma unroll
    for (int k = 2; k <= 64; k <<= 1) {
        #pragma unroll
        for (int jj = k >> 1; jj >= 1; jj >>= 1) {
            const int pv = __shfl_xor(v, jj);
            const bool keepmin = ((lane & jj) == 0) == ((lane & k) == 0);
            v = keepmin ? min(v, pv) : max(v, pv);
        }
    }
    if (lane < MAXNB) out_idx[p * MAXNB + lane] = (lane < count) ? v : -1;

    // Plain store of the full count; maxred (next dispatch, same stream)
    // reduces. No atomics, no fences, no block barrier.
    if (lane == 0) wavemax[p] = count;
}

// ---------- maxred: 1 block, reduce 8192 wave counts -> actual_max ----------
__global__ __launch_bounds__(1024) void maxred_kernel(const int* __restrict__ wavemax,
                                                      int* __restrict__ out_max) {
    __shared__ int wm[16];
    const int t    = threadIdx.x;
    const int lane = t & 63;
    const int wv   = t >> 6;
    const int4* w4 = (const int4*)wavemax;            // 2048 int4 = 8192 ints
    const int4 a = w4[t];
    const int4 b = w4[t + 1024];
    int mx = max(max(max(a.x, a.y), max(a.z, a.w)),
                 max(max(b.x, b.y), max(b.z, b.w)));
    #pragma unroll
    for (int off = 32; off > 0; off >>= 1) mx = max(mx, __shfl_xor(mx, off));
    if (lane == 0) wm[wv] = mx;
    __syncthreads();
    if (t == 0) {
        int m2 = wm[0];
        #pragma unroll
        for (int k = 1; k < 16; ++k) m2 = max(m2, wm[k]);
        *out_max = m2;
    }
}

extern "C" void kernel_launch(void* const* d_in, const int* in_sizes, int n_in,
                              void* d_out, int out_size, void* d_ws, size_t ws_size,
                              hipStream_t stream) {
    const float* pos = (const float*)d_in[0];   // [8192, 3] f32
    int* out = (int*)d_out;

    int*  out_idx = out;                        // [N*32]
    int4* cell4   = (int4*)(out + N * MAXNB);   // cell_indices region (zeroed by query)
    int*  out_max = out + N * MAXNB * 4;        // scalar

    // Scratch in d_ws (~181 KB used; the 256 MiB ws poison fill shows it is
    // far larger). Every byte used is written before read within each replay.
    char*   ws      = (char*)d_ws;
    float4* sorted  = (float4*)ws;              // 131072 B, 16B aligned
    int*    start_g = (int*)(ws + 131072);      // 4097 ints
    int*    wavemax = (int*)(ws + 147968);      // 8192 ints, 16B aligned

    build_kernel <<<1, 1024, 0, stream>>>(pos, start_g, sorted);
    query_kernel <<<QBLOCKS, 256, 0, stream>>>(pos, sorted, start_g, out_idx, cell4, wavemax);
    maxred_kernel<<<1, 1024, 0, stream>>>(wavemax, out_max);
}